// Round 1
// baseline (173.103 us; speedup 1.0000x reference)
//
#include <hip/hip_runtime.h>

#define BLOCK 256

typedef float f4u __attribute__((ext_vector_type(4), aligned(4)));  // 4B-aligned float4

// R8: identical compute kernel to R7. The fix is in kernel_launch: the old
// code zeroed sizeof(float)*out_size bytes, and out_size is the output
// BUFFER size (2^28), not the logical element count (1). That memset
// expanded to 1 GiB = four 256 MiB fillBufferAligned dispatches (~162 us,
// 94% of measured time). We only ever atomicAdd into out[0], so zeroing
// 4 bytes is sufficient.
__device__ __forceinline__ f4u ntload(const float* p) {
    return __builtin_nontemporal_load(reinterpret_cast<const f4u*>(p));
}

__global__ __launch_bounds__(BLOCK) void chi2_fused(
    const float* __restrict__ fluct,
    const float* __restrict__ ivar,
    const float* __restrict__ outp,
    const int*  __restrict__ ovl,      // (B,4) int32: s_in, e_in, s_out, e_out
    float* __restrict__ out,           // out[0] pre-zeroed (4 bytes)
    int L, float inv_B)
{
    const int wave = (blockIdx.x * BLOCK + threadIdx.x) >> 6;  // = sample
    const int lane = threadIdx.x & 63;

    const int4 o   = reinterpret_cast<const int4*>(ovl)[wave];
    const int s_in = o.x, e_in = o.y, s_out = o.z;
    const int len  = e_in - s_in;

    const float* __restrict__ xp = fluct + (size_t)wave * L + s_in;
    const float* __restrict__ wp = ivar  + (size_t)wave * L + s_in;
    const float* __restrict__ yp = outp  + (size_t)wave * L + s_out;

    const int n4 = len >> 2;               // full dwordx4 chunks, 4B-aligned

    float a0 = 0.f, a1 = 0.f, a2 = 0.f, a3 = 0.f;
    int c = lane;
    // Main: 4 chunks x 3 streams = 12 nontemporal wide loads in flight.
    for (; c + 192 < n4; c += 256) {
        const f4u xv0 = ntload(xp + 4 * c);
        const f4u xv1 = ntload(xp + 4 * (c +  64));
        const f4u xv2 = ntload(xp + 4 * (c + 128));
        const f4u xv3 = ntload(xp + 4 * (c + 192));
        const f4u yv0 = ntload(yp + 4 * c);
        const f4u yv1 = ntload(yp + 4 * (c +  64));
        const f4u yv2 = ntload(yp + 4 * (c + 128));
        const f4u yv3 = ntload(yp + 4 * (c + 192));
        const f4u wv0 = ntload(wp + 4 * c);
        const f4u wv1 = ntload(wp + 4 * (c +  64));
        const f4u wv2 = ntload(wp + 4 * (c + 128));
        const f4u wv3 = ntload(wp + 4 * (c + 192));
        #pragma unroll
        for (int e = 0; e < 4; ++e) {
            const float d0 = xv0[e] - yv0[e];
            const float d1 = xv1[e] - yv1[e];
            const float d2 = xv2[e] - yv2[e];
            const float d3 = xv3[e] - yv3[e];
            a0 = fmaf(d0 * d0, wv0[e], a0);
            a1 = fmaf(d1 * d1, wv1[e], a1);
            a2 = fmaf(d2 * d2, wv2[e], a2);
            a3 = fmaf(d3 * d3, wv3[e], a3);
        }
    }
    // Remainder chunks.
    for (; c < n4; c += 64) {
        const f4u xv = ntload(xp + 4 * c);
        const f4u yv = ntload(yp + 4 * c);
        const f4u wv = ntload(wp + 4 * c);
        #pragma unroll
        for (int e = 0; e < 4; ++e) {
            const float d = xv[e] - yv[e];
            a0 = fmaf(d * d, wv[e], a0);
        }
    }
    // Scalar tail (0..3 elements).
    const int done = n4 << 2;
    if (lane < (len & 3)) {
        const float d = xp[done + lane] - yp[done + lane];
        a0 = fmaf(d * d, wp[done + lane], a0);
    }

    float acc = (a0 + a1) + (a2 + a3);

    // wave reduction
    #pragma unroll
    for (int off = 32; off > 0; off >>= 1)
        acc += __shfl_down(acc, off, 64);

    // block reduction: 4 wave-leaders -> LDS -> one atomic per block.
    __shared__ float sacc[BLOCK / 64];
    if (lane == 0) sacc[threadIdx.x >> 6] = (acc / (float)len) * inv_B;
    __syncthreads();

    if (threadIdx.x == 0) {
        float s = 0.f;
        #pragma unroll
        for (int i = 0; i < BLOCK / 64; ++i) s += sacc[i];
        atomicAdd(out, s);
    }
}

extern "C" void kernel_launch(void* const* d_in, const int* in_sizes, int n_in,
                              void* d_out, int out_size, void* d_ws, size_t ws_size,
                              hipStream_t stream) {
    const float* fluct = (const float*)d_in[0];  // (B,1,L) f32
    const float* ivar  = (const float*)d_in[1];  // (B,1,L) f32
    const float* outp  = (const float*)d_in[2];  // (B,1,L) f32
    const int*   ovl   = (const int*)d_in[3];    // (B,4)   i32

    const int B = in_sizes[3] / 4;               // 4096
    const int L = in_sizes[0] / B;               // 4096

    // Zero ONLY the 4 bytes we accumulate into. The logical output is a
    // single f32; zeroing sizeof(float)*out_size expanded to a 1 GiB fill
    // (4x 256 MiB fillBufferAligned dispatches = ~162 us of the previous
    // 172.8 us measurement).
    hipMemsetAsync(d_out, 0, sizeof(float), stream);

    const int waves_per_block = BLOCK / 64;      // 4
    chi2_fused<<<B / waves_per_block, BLOCK, 0, stream>>>(
        fluct, ivar, outp, ovl, (float*)d_out, L, 1.0f / (float)B);
}